// Round 1
// baseline (668.929 us; speedup 1.0000x reference)
//
#include <hip/hip_runtime.h>
#include <math.h>

typedef __bf16 bf16;
typedef __bf16 bfrag __attribute__((ext_vector_type(8)));
typedef __bf16 bf4 __attribute__((ext_vector_type(4)));
typedef float f4 __attribute__((ext_vector_type(4)));

#define DEV static __device__ __forceinline__

DEV f4 MFMA(bfrag a, bfrag b, f4 c) {
  return __builtin_amdgcn_mfma_f32_16x16x32_bf16(a, b, c, 0, 0, 0);
}

// ---------------- fp32 -> bf16 convert (x4 vectorized) ----------------
__global__ void cvt_bf16(const float* __restrict__ in, bf16* __restrict__ out, int n4) {
  int i = blockIdx.x * blockDim.x + threadIdx.x;
  if (i >= n4) return;
  float4 v = reinterpret_cast<const float4*>(in)[i];
  bf4 o;
  o[0] = (bf16)v.x; o[1] = (bf16)v.y; o[2] = (bf16)v.z; o[3] = (bf16)v.w;
  reinterpret_cast<bf4*>(out)[i] = o;
}

// ---------------- mask -> additive bias ----------------
__global__ void maskbias_k(const int* __restrict__ mask, float* __restrict__ mb, int n) {
  int i = blockIdx.x * blockDim.x + threadIdx.x;
  if (i < n) mb[i] = (mask[i] > 0) ? 0.f : -1e9f;
}

// ---------------- GEMM: C[M,N] = A[M,K] @ W[N,K]^T + bias ----------------
// A row-major lda=K stride, W row-major (nn.Linear layout), both bf16.
// Block: 4 waves (2x2), tile 64x64, per-wave 32x32 via 2x2 mfma frags.
template<int OUTF32>
__global__ __launch_bounds__(256) void gemm_nt(
    const bf16* __restrict__ A, int lda,
    const bf16* __restrict__ W, int ldw,
    const float* __restrict__ bias,
    void* __restrict__ C, int ldc,
    int N64, int K) {
  int lane = threadIdx.x & 63;
  int w = threadIdx.x >> 6;
  int lrow = lane & 15, lgrp = lane >> 4;
  int tn = blockIdx.x % N64, tm = blockIdx.x / N64;
  int m0 = tm * 64 + (w >> 1) * 32;
  int n0 = tn * 64 + (w & 1) * 32;
  const bf16* Ab = A + (size_t)m0 * lda + lgrp * 8;
  const bf16* Wb = W + (size_t)n0 * ldw + lgrp * 8;
  f4 acc[2][2] = {};
  for (int k0 = 0; k0 < K; k0 += 32) {
    bfrag a0 = *(const bfrag*)(Ab + (size_t)lrow * lda + k0);
    bfrag a1 = *(const bfrag*)(Ab + (size_t)(lrow + 16) * lda + k0);
    bfrag b0 = *(const bfrag*)(Wb + (size_t)lrow * ldw + k0);
    bfrag b1 = *(const bfrag*)(Wb + (size_t)(lrow + 16) * ldw + k0);
    acc[0][0] = MFMA(a0, b0, acc[0][0]);
    acc[0][1] = MFMA(a0, b1, acc[0][1]);
    acc[1][0] = MFMA(a1, b0, acc[1][0]);
    acc[1][1] = MFMA(a1, b1, acc[1][1]);
  }
#pragma unroll
  for (int mi = 0; mi < 2; mi++)
#pragma unroll
    for (int nj = 0; nj < 2; nj++) {
      int col = n0 + nj * 16 + lrow;
      float bv = bias[col];
      int rowb = m0 + mi * 16 + lgrp * 4;
#pragma unroll
      for (int i = 0; i < 4; i++) {
        float v = acc[mi][nj][i] + bv;
        if (OUTF32)
          ((float*)C)[(size_t)(rowb + i) * ldc + col] = v;
        else
          ((bf16*)C)[(size_t)(rowb + i) * ldc + col] = (bf16)v;
      }
    }
}

// ---------------- V transpose: Vt[b][h][d][s] = V[b][s][coff + h*64 + d] ----------------
__global__ __launch_bounds__(256) void vtrans(const bf16* __restrict__ V, int rs, int coff,
                                              bf16* __restrict__ Vt, int H, int S) {
  int nst = S / 64;
  int st = blockIdx.x % nst;
  int h = (blockIdx.x / nst) % H;
  int b = blockIdx.x / (nst * H);
  __shared__ bf16 tile[64][72];
  int t = threadIdx.x;
  int r = t >> 2, c = t & 3;
  const bf16* src = V + ((size_t)b * S + st * 64 + r) * rs + coff + h * 64 + c * 16;
  bfrag v0 = *(const bfrag*)(src);
  bfrag v1 = *(const bfrag*)(src + 8);
  *(bfrag*)&tile[r][c * 16] = v0;
  *(bfrag*)&tile[r][c * 16 + 8] = v1;
  __syncthreads();
  // thread t now writes d-row r, s-chunk c
  bf16* dst = Vt + (((size_t)b * H + h) * 64 + r) * S + st * 64 + c * 16;
  bfrag o0, o1;
#pragma unroll
  for (int j = 0; j < 8; j++) {
    o0[j] = tile[c * 16 + j][r];
    o1[j] = tile[c * 16 + 8 + j][r];
  }
  *(bfrag*)dst = o0;
  *(bfrag*)(dst + 8) = o1;
}

// ---------------- flash attention ----------------
// Q/K: [B,S,rs] bf16, head col offset h*64 (K pointer may carry extra base offset).
// Vt: [B,H,64,S]. bias: [B,S] additive per-key (includes mask and ALPHA*surv).
// O: [B,S,ors] at col h*64. Per block: 64 q rows for one (b,h); wave w owns 16 rows.
__global__ __launch_bounds__(256) void flash_k(
    const bf16* __restrict__ Q, const bf16* __restrict__ Kp, int rs,
    const bf16* __restrict__ Vt, const float* __restrict__ bias,
    bf16* __restrict__ O, int ors, int H, int S, float scale) {
  int nqt = S / 64;
  int qt = blockIdx.x % nqt;
  int h = (blockIdx.x / nqt) % H;
  int b = blockIdx.x / (nqt * H);
  int lane = threadIdx.x & 63, w = threadIdx.x >> 6;
  int lrow = lane & 15, lgrp = lane >> 4;
  int q0 = qt * 64 + w * 16;

  const bf16* Qb = Q + ((size_t)b * S + q0) * rs + h * 64;
  bfrag qf0 = *(const bfrag*)(Qb + (size_t)lrow * rs + lgrp * 8);
  bfrag qf1 = *(const bfrag*)(Qb + (size_t)lrow * rs + 32 + lgrp * 8);
  const bf16* Kb = Kp + (size_t)b * S * rs + h * 64;
  const bf16* Vb = Vt + ((size_t)b * H + h) * 64 * (size_t)S;
  const float* biasb = bias + (size_t)b * S;

  __shared__ bf16 P[4][16][72];
  f4 acc[4] = {};
  float m[4], l[4];
#pragma unroll
  for (int i = 0; i < 4; i++) { m[i] = -INFINITY; l[i] = 0.f; }

  for (int kt = 0; kt < S; kt += 64) {
    f4 s[4];
    float bv[4];
#pragma unroll
    for (int cf = 0; cf < 4; cf++) {
      const bf16* kr = Kb + (size_t)(kt + cf * 16 + lrow) * rs + lgrp * 8;
      bfrag k0 = *(const bfrag*)(kr);
      bfrag k1 = *(const bfrag*)(kr + 32);
      f4 z = {0.f, 0.f, 0.f, 0.f};
      z = MFMA(qf0, k0, z);
      z = MFMA(qf1, k1, z);
      s[cf] = z;
      bv[cf] = biasb[kt + cf * 16 + lrow];
    }
#pragma unroll
    for (int cf = 0; cf < 4; cf++)
#pragma unroll
      for (int i = 0; i < 4; i++) s[cf][i] = s[cf][i] * scale + bv[cf];

    float p[4][4];
#pragma unroll
    for (int i = 0; i < 4; i++) {
      float mx = fmaxf(fmaxf(s[0][i], s[1][i]), fmaxf(s[2][i], s[3][i]));
      mx = fmaxf(mx, __shfl_xor(mx, 1));
      mx = fmaxf(mx, __shfl_xor(mx, 2));
      mx = fmaxf(mx, __shfl_xor(mx, 4));
      mx = fmaxf(mx, __shfl_xor(mx, 8));
      float mn = fmaxf(m[i], mx);
      float sc = __expf(m[i] - mn);
      m[i] = mn;
      float rsum = 0.f;
#pragma unroll
      for (int cf = 0; cf < 4; cf++) { p[cf][i] = __expf(s[cf][i] - mn); rsum += p[cf][i]; }
      rsum += __shfl_xor(rsum, 1);
      rsum += __shfl_xor(rsum, 2);
      rsum += __shfl_xor(rsum, 4);
      rsum += __shfl_xor(rsum, 8);
      l[i] = l[i] * sc + rsum;
#pragma unroll
      for (int df = 0; df < 4; df++) acc[df][i] *= sc;
    }
    // P -> LDS (per-wave, rows = q 0..15 of this wave's tile)
#pragma unroll
    for (int cf = 0; cf < 4; cf++)
#pragma unroll
      for (int i = 0; i < 4; i++)
        P[w][lgrp * 4 + i][cf * 16 + lrow] = (bf16)p[cf][i];
    // PV
#pragma unroll
    for (int ks = 0; ks < 2; ks++) {
      bfrag pa = *(const bfrag*)&P[w][lrow][ks * 32 + lgrp * 8];
#pragma unroll
      for (int df = 0; df < 4; df++) {
        const bf16* vr = Vb + (size_t)(df * 16 + lrow) * S + kt + ks * 32 + lgrp * 8;
        bfrag vf = *(const bfrag*)vr;
        acc[df] = MFMA(pa, vf, acc[df]);
      }
    }
  }
  bf16* Ob = O + ((size_t)b * S + q0) * ors + h * 64;
#pragma unroll
  for (int df = 0; df < 4; df++)
#pragma unroll
    for (int i = 0; i < 4; i++) {
      float v = acc[df][i] / l[i];
      Ob[(size_t)(lgrp * 4 + i) * ors + df * 16 + lrow] = (bf16)v;
    }
}

// ---------------- fused scorer MLPs -> biasMain ----------------
// One wave per row. lane j computes hidden units j and j+64 of each 256->128->1 MLP.
__global__ __launch_bounds__(256) void mlp_surv(
    const bf16* __restrict__ h1,
    const float* __restrict__ nw1, const float* __restrict__ nb1,
    const float* __restrict__ nw2, const float* __restrict__ nb2,
    const float* __restrict__ mw1, const float* __restrict__ mb1,
    const float* __restrict__ mw2, const float* __restrict__ mb2,
    const float* __restrict__ dw1, const float* __restrict__ db1,
    const float* __restrict__ dw2, const float* __restrict__ db2,
    const float* __restrict__ maskBias, float* __restrict__ biasMain) {
  int w = threadIdx.x >> 6, lane = threadIdx.x & 63;
  int row = blockIdx.x * 4 + w;
  __shared__ float hs[4][256];
  for (int j = lane; j < 256; j += 64) hs[w][j] = (float)h1[(size_t)row * 256 + j];
  __syncthreads();
  const float* W1[3] = {nw1, mw1, dw1};
  const float* B1[3] = {nb1, mb1, db1};
  const float* W2[3] = {nw2, mw2, dw2};
  const float* B2[3] = {nb2, mb2, db2};
  float outs[3];
#pragma unroll
  for (int t = 0; t < 3; t++) {
    float acc = 0.f;
#pragma unroll
    for (int jj = 0; jj < 2; jj++) {
      int j = lane + jj * 64;
      const float4* wr = (const float4*)(W1[t] + (size_t)j * 256);
      const float4* hr = (const float4*)hs[w];
      float s = B1[t][j];
      for (int kk = 0; kk < 64; kk++) {
        float4 a = wr[kk], hv = hr[kk];
        s += a.x * hv.x + a.y * hv.y + a.z * hv.z + a.w * hv.w;
      }
      float hid = fmaxf(s, 0.f);
      acc += W2[t][j] * hid;
    }
    for (int msk = 1; msk < 64; msk <<= 1) acc += __shfl_xor(acc, msk);
    outs[t] = acc + B2[t][0];
  }
  if (lane == 0) {
    float xn = outs[0];
    float n = (xn > 20.f) ? xn : log1pf(__expf(xn));
    float mu = 1.f / (1.f + __expf(-outs[1]));
    float delta = fmaxf(outs[2], 0.f);
    float surv = logf(n + 1e-8f) + logf(mu + 1e-8f) - delta;
    biasMain[row] = 0.1f * surv + maskBias[row];
  }
}

extern "C" void kernel_launch(void* const* d_in, const int* in_sizes, int n_in,
                              void* d_out, int out_size, void* d_ws, size_t ws_size,
                              hipStream_t stream) {
  const int B = 2, S = 2048, H = 768, I = 256;
  const int NH = 12, SNH = 4;
  const int M = B * S;  // 4096

  const float* x = (const float*)d_in[0];
  const int* mask = (const int*)d_in[1];
  const float* qw = (const float*)d_in[2];
  const float* qb = (const float*)d_in[3];
  const float* kw = (const float*)d_in[4];
  const float* kb = (const float*)d_in[5];
  const float* vw = (const float*)d_in[6];
  const float* vb = (const float*)d_in[7];
  const float* ow = (const float*)d_in[8];
  const float* ob = (const float*)d_in[9];
  const float* sp_w = (const float*)d_in[10];
  const float* sp_b = (const float*)d_in[11];
  const float* sa_in_w = (const float*)d_in[12];
  const float* sa_in_b = (const float*)d_in[13];
  const float* sa_out_w = (const float*)d_in[14];
  const float* sa_out_b = (const float*)d_in[15];
  const float* nw1 = (const float*)d_in[16];
  const float* nb1 = (const float*)d_in[17];
  const float* nw2 = (const float*)d_in[18];
  const float* nb2 = (const float*)d_in[19];
  const float* mw1 = (const float*)d_in[20];
  const float* mb1 = (const float*)d_in[21];
  const float* mw2 = (const float*)d_in[22];
  const float* mb2 = (const float*)d_in[23];
  const float* dw1 = (const float*)d_in[24];
  const float* db1 = (const float*)d_in[25];
  const float* dw2 = (const float*)d_in[26];
  const float* db2 = (const float*)d_in[27];

  char* ws = (char*)d_ws;
  size_t off = 0;
  auto alloc = [&](size_t bytes) -> void* {
    void* p = ws + off;
    off += (bytes + 255) & ~(size_t)255;
    return p;
  };

  // persistent
  bf16* xb = (bf16*)alloc((size_t)M * H * 2);
  bf16* wqb = (bf16*)alloc((size_t)H * H * 2);
  bf16* wkb = (bf16*)alloc((size_t)H * H * 2);
  bf16* wvb = (bf16*)alloc((size_t)H * H * 2);
  bf16* wob = (bf16*)alloc((size_t)H * H * 2);
  bf16* spwb = (bf16*)alloc((size_t)I * H * 2);
  bf16* sainb = (bf16*)alloc((size_t)(3 * I) * I * 2);
  bf16* saoutb = (bf16*)alloc((size_t)I * I * 2);
  float* maskBias = (float*)alloc((size_t)M * 4);
  float* biasMain = (float*)alloc((size_t)M * 4);

  size_t offMark = off;
  // phase A (scorer) scratch
  bf16* h0 = (bf16*)alloc((size_t)M * I * 2);
  bf16* qkv_s = (bf16*)alloc((size_t)M * (3 * I) * 2);
  bf16* vt_s = (bf16*)alloc((size_t)B * SNH * 64 * S * 2);
  bf16* attn_s = (bf16*)alloc((size_t)M * I * 2);
  bf16* h1 = (bf16*)alloc((size_t)M * I * 2);
  // phase B (main) scratch — overlays phase A (stream-serialized, phase A dead by then)
  off = offMark;
  bf16* Qm = (bf16*)alloc((size_t)M * H * 2);
  bf16* Km = (bf16*)alloc((size_t)M * H * 2);
  bf16* Vm = (bf16*)alloc((size_t)M * H * 2);
  bf16* vt_m = (bf16*)alloc((size_t)B * NH * 64 * S * 2);
  bf16* attn_m = (bf16*)alloc((size_t)M * H * 2);
  (void)ws_size; (void)in_sizes; (void)n_in; (void)out_size;

  auto cdiv = [](int a, int b) { return (a + b - 1) / b; };

  // converts
  cvt_bf16<<<cdiv(M * H / 4, 256), 256, 0, stream>>>(x, xb, M * H / 4);
  cvt_bf16<<<cdiv(H * H / 4, 256), 256, 0, stream>>>(qw, wqb, H * H / 4);
  cvt_bf16<<<cdiv(H * H / 4, 256), 256, 0, stream>>>(kw, wkb, H * H / 4);
  cvt_bf16<<<cdiv(H * H / 4, 256), 256, 0, stream>>>(vw, wvb, H * H / 4);
  cvt_bf16<<<cdiv(H * H / 4, 256), 256, 0, stream>>>(ow, wob, H * H / 4);
  cvt_bf16<<<cdiv(I * H / 4, 256), 256, 0, stream>>>(sp_w, spwb, I * H / 4);
  cvt_bf16<<<cdiv(3 * I * I / 4, 256), 256, 0, stream>>>(sa_in_w, sainb, 3 * I * I / 4);
  cvt_bf16<<<cdiv(I * I / 4, 256), 256, 0, stream>>>(sa_out_w, saoutb, I * I / 4);
  maskbias_k<<<cdiv(M, 256), 256, 0, stream>>>(mask, maskBias, M);

  // ---- scorer branch ----
  gemm_nt<0><<<(M / 64) * (I / 64), 256, 0, stream>>>(xb, H, spwb, H, sp_b, h0, I, I / 64, H);
  gemm_nt<0><<<(M / 64) * ((3 * I) / 64), 256, 0, stream>>>(h0, I, sainb, I, sa_in_b, qkv_s,
                                                            3 * I, (3 * I) / 64, I);
  vtrans<<<B * SNH * (S / 64), 256, 0, stream>>>(qkv_s, 3 * I, 2 * I, vt_s, SNH, S);
  flash_k<<<B * SNH * (S / 64), 256, 0, stream>>>(qkv_s, qkv_s + I, 3 * I, vt_s, maskBias,
                                                  attn_s, I, SNH, S, 0.125f);
  gemm_nt<0><<<(M / 64) * (I / 64), 256, 0, stream>>>(attn_s, I, saoutb, I, sa_out_b, h1, I,
                                                      I / 64, I);
  mlp_surv<<<M / 4, 256, 0, stream>>>(h1, nw1, nb1, nw2, nb2, mw1, mb1, mw2, mb2, dw1, db1,
                                      dw2, db2, maskBias, biasMain);

  // ---- main branch ----
  gemm_nt<0><<<(M / 64) * (H / 64), 256, 0, stream>>>(xb, H, wqb, H, qb, Qm, H, H / 64, H);
  gemm_nt<0><<<(M / 64) * (H / 64), 256, 0, stream>>>(xb, H, wkb, H, kb, Km, H, H / 64, H);
  gemm_nt<0><<<(M / 64) * (H / 64), 256, 0, stream>>>(xb, H, wvb, H, vb, Vm, H, H / 64, H);
  vtrans<<<B * NH * (S / 64), 256, 0, stream>>>(Vm, H, 0, vt_m, NH, S);
  flash_k<<<B * NH * (S / 64), 256, 0, stream>>>(Qm, Km, H, vt_m, biasMain, attn_m, H, NH, S,
                                                 0.125f);
  gemm_nt<1><<<(M / 64) * (H / 64), 256, 0, stream>>>(attn_m, H, wob, H, ob, d_out, H, H / 64,
                                                      H);
}

// Round 2
// 512.238 us; speedup vs baseline: 1.3059x; 1.3059x over previous
//
#include <hip/hip_runtime.h>
#include <math.h>

typedef __bf16 bf16;
typedef __bf16 bfrag __attribute__((ext_vector_type(8)));
typedef __bf16 bf4 __attribute__((ext_vector_type(4)));
typedef float f4 __attribute__((ext_vector_type(4)));

#define DEV static __device__ __forceinline__

DEV f4 MFMA(bfrag a, bfrag b, f4 c) {
  return __builtin_amdgcn_mfma_f32_16x16x32_bf16(a, b, c, 0, 0, 0);
}

// ---------------- fp32 -> bf16 convert (x4 vectorized) ----------------
__global__ void cvt_bf16(const float* __restrict__ in, bf16* __restrict__ out, int n4) {
  int i = blockIdx.x * blockDim.x + threadIdx.x;
  if (i >= n4) return;
  float4 v = reinterpret_cast<const float4*>(in)[i];
  bf4 o;
  o[0] = (bf16)v.x; o[1] = (bf16)v.y; o[2] = (bf16)v.z; o[3] = (bf16)v.w;
  reinterpret_cast<bf4*>(out)[i] = o;
}

// ---------------- mask -> additive bias ----------------
__global__ void maskbias_k(const int* __restrict__ mask, float* __restrict__ mb, int n) {
  int i = blockIdx.x * blockDim.x + threadIdx.x;
  if (i < n) mb[i] = (mask[i] > 0) ? 0.f : -1e9f;
}

// ---------------- GEMM: C[M,N] = act(A[M,K] @ W[N,K]^T + bias) ----------------
// A row-major lda=K stride, W row-major (nn.Linear layout), both bf16.
// Block: 4 waves (2x2), tile 64x64, per-wave 32x32 via 2x2 mfma frags.
template<int OUTF32, int RELU>
__global__ __launch_bounds__(256) void gemm_nt(
    const bf16* __restrict__ A, int lda,
    const bf16* __restrict__ W, int ldw,
    const float* __restrict__ bias,
    void* __restrict__ C, int ldc,
    int N64, int K) {
  int lane = threadIdx.x & 63;
  int w = threadIdx.x >> 6;
  int lrow = lane & 15, lgrp = lane >> 4;
  int tn = blockIdx.x % N64, tm = blockIdx.x / N64;
  int m0 = tm * 64 + (w >> 1) * 32;
  int n0 = tn * 64 + (w & 1) * 32;
  const bf16* Ab = A + (size_t)m0 * lda + lgrp * 8;
  const bf16* Wb = W + (size_t)n0 * ldw + lgrp * 8;
  f4 acc[2][2] = {};
  for (int k0 = 0; k0 < K; k0 += 32) {
    bfrag a0 = *(const bfrag*)(Ab + (size_t)lrow * lda + k0);
    bfrag a1 = *(const bfrag*)(Ab + (size_t)(lrow + 16) * lda + k0);
    bfrag b0 = *(const bfrag*)(Wb + (size_t)lrow * ldw + k0);
    bfrag b1 = *(const bfrag*)(Wb + (size_t)(lrow + 16) * ldw + k0);
    acc[0][0] = MFMA(a0, b0, acc[0][0]);
    acc[0][1] = MFMA(a0, b1, acc[0][1]);
    acc[1][0] = MFMA(a1, b0, acc[1][0]);
    acc[1][1] = MFMA(a1, b1, acc[1][1]);
  }
#pragma unroll
  for (int mi = 0; mi < 2; mi++)
#pragma unroll
    for (int nj = 0; nj < 2; nj++) {
      int col = n0 + nj * 16 + lrow;
      float bv = bias[col];
      int rowb = m0 + mi * 16 + lgrp * 4;
#pragma unroll
      for (int i = 0; i < 4; i++) {
        float v = acc[mi][nj][i] + bv;
        if (RELU) v = fmaxf(v, 0.f);
        if (OUTF32)
          ((float*)C)[(size_t)(rowb + i) * ldc + col] = v;
        else
          ((bf16*)C)[(size_t)(rowb + i) * ldc + col] = (bf16)v;
      }
    }
}

// ---------------- V transpose: Vt[b][h][d][s] = V[b][s][coff + h*64 + d] ----------------
__global__ __launch_bounds__(256) void vtrans(const bf16* __restrict__ V, int rs, int coff,
                                              bf16* __restrict__ Vt, int H, int S) {
  int nst = S / 64;
  int st = blockIdx.x % nst;
  int h = (blockIdx.x / nst) % H;
  int b = blockIdx.x / (nst * H);
  __shared__ bf16 tile[64][72];
  int t = threadIdx.x;
  int r = t >> 2, c = t & 3;
  const bf16* src = V + ((size_t)b * S + st * 64 + r) * rs + coff + h * 64 + c * 16;
  bfrag v0 = *(const bfrag*)(src);
  bfrag v1 = *(const bfrag*)(src + 8);
  *(bfrag*)&tile[r][c * 16] = v0;
  *(bfrag*)&tile[r][c * 16 + 8] = v1;
  __syncthreads();
  // thread t now writes d-row r, s-chunk c
  bf16* dst = Vt + (((size_t)b * H + h) * 64 + r) * S + st * 64 + c * 16;
  bfrag o0, o1;
#pragma unroll
  for (int j = 0; j < 8; j++) {
    o0[j] = tile[c * 16 + j][r];
    o1[j] = tile[c * 16 + 8 + j][r];
  }
  *(bfrag*)dst = o0;
  *(bfrag*)(dst + 8) = o1;
}

// ---------------- flash attention ----------------
// Q/K: [B,S,rs] bf16, head col offset h*64 (K pointer may carry extra base offset).
// Vt: [B,H,64,S]. bias: [B,S] additive per-key (includes mask and ALPHA*surv).
// O: [B,S,ors] at col h*64. Per block: 64 q rows for one (b,h); wave w owns 16 rows.
__global__ __launch_bounds__(256) void flash_k(
    const bf16* __restrict__ Q, const bf16* __restrict__ Kp, int rs,
    const bf16* __restrict__ Vt, const float* __restrict__ bias,
    bf16* __restrict__ O, int ors, int H, int S, float scale) {
  int nqt = S / 64;
  int qt = blockIdx.x % nqt;
  int h = (blockIdx.x / nqt) % H;
  int b = blockIdx.x / (nqt * H);
  int lane = threadIdx.x & 63, w = threadIdx.x >> 6;
  int lrow = lane & 15, lgrp = lane >> 4;
  int q0 = qt * 64 + w * 16;

  const bf16* Qb = Q + ((size_t)b * S + q0) * rs + h * 64;
  bfrag qf0 = *(const bfrag*)(Qb + (size_t)lrow * rs + lgrp * 8);
  bfrag qf1 = *(const bfrag*)(Qb + (size_t)lrow * rs + 32 + lgrp * 8);
  const bf16* Kb = Kp + (size_t)b * S * rs + h * 64;
  const bf16* Vb = Vt + ((size_t)b * H + h) * 64 * (size_t)S;
  const float* biasb = bias + (size_t)b * S;

  __shared__ bf16 P[4][16][72];
  f4 acc[4] = {};
  float m[4], l[4];
#pragma unroll
  for (int i = 0; i < 4; i++) { m[i] = -INFINITY; l[i] = 0.f; }

  for (int kt = 0; kt < S; kt += 64) {
    f4 s[4];
    float bv[4];
#pragma unroll
    for (int cf = 0; cf < 4; cf++) {
      const bf16* kr = Kb + (size_t)(kt + cf * 16 + lrow) * rs + lgrp * 8;
      bfrag k0 = *(const bfrag*)(kr);
      bfrag k1 = *(const bfrag*)(kr + 32);
      f4 z = {0.f, 0.f, 0.f, 0.f};
      z = MFMA(qf0, k0, z);
      z = MFMA(qf1, k1, z);
      s[cf] = z;
      bv[cf] = biasb[kt + cf * 16 + lrow];
    }
#pragma unroll
    for (int cf = 0; cf < 4; cf++)
#pragma unroll
      for (int i = 0; i < 4; i++) s[cf][i] = s[cf][i] * scale + bv[cf];

    float p[4][4];
#pragma unroll
    for (int i = 0; i < 4; i++) {
      float mx = fmaxf(fmaxf(s[0][i], s[1][i]), fmaxf(s[2][i], s[3][i]));
      mx = fmaxf(mx, __shfl_xor(mx, 1));
      mx = fmaxf(mx, __shfl_xor(mx, 2));
      mx = fmaxf(mx, __shfl_xor(mx, 4));
      mx = fmaxf(mx, __shfl_xor(mx, 8));
      float mn = fmaxf(m[i], mx);
      float sc = __expf(m[i] - mn);
      m[i] = mn;
      float rsum = 0.f;
#pragma unroll
      for (int cf = 0; cf < 4; cf++) { p[cf][i] = __expf(s[cf][i] - mn); rsum += p[cf][i]; }
      rsum += __shfl_xor(rsum, 1);
      rsum += __shfl_xor(rsum, 2);
      rsum += __shfl_xor(rsum, 4);
      rsum += __shfl_xor(rsum, 8);
      l[i] = l[i] * sc + rsum;
#pragma unroll
      for (int df = 0; df < 4; df++) acc[df][i] *= sc;
    }
    // P -> LDS (per-wave, rows = q 0..15 of this wave's tile)
#pragma unroll
    for (int cf = 0; cf < 4; cf++)
#pragma unroll
      for (int i = 0; i < 4; i++)
        P[w][lgrp * 4 + i][cf * 16 + lrow] = (bf16)p[cf][i];
    // PV
#pragma unroll
    for (int ks = 0; ks < 2; ks++) {
      bfrag pa = *(const bfrag*)&P[w][lrow][ks * 32 + lgrp * 8];
#pragma unroll
      for (int df = 0; df < 4; df++) {
        const bf16* vr = Vb + (size_t)(df * 16 + lrow) * S + kt + ks * 32 + lgrp * 8;
        bfrag vf = *(const bfrag*)vr;
        acc[df] = MFMA(pa, vf, acc[df]);
      }
    }
  }
  bf16* Ob = O + ((size_t)b * S + q0) * ors + h * 64;
#pragma unroll
  for (int df = 0; df < 4; df++)
#pragma unroll
    for (int i = 0; i < 4; i++) {
      float v = acc[df][i] / l[i];
      Ob[(size_t)(lgrp * 4 + i) * ors + df * 16 + lrow] = (bf16)v;
    }
}

// ---------------- survival epilogue: three 128-dots + softplus/sigmoid/log ----------------
// hid: [M,384] bf16 = relu(h1 @ [nw1;mw1;dw1]^T + b1). One wave per row.
__global__ __launch_bounds__(256) void surv_k(
    const bf16* __restrict__ hid,
    const float* __restrict__ nw2, const float* __restrict__ nb2,
    const float* __restrict__ mw2, const float* __restrict__ mb2,
    const float* __restrict__ dw2, const float* __restrict__ db2,
    const float* __restrict__ maskBias, float* __restrict__ biasMain) {
  int w = threadIdx.x >> 6, lane = threadIdx.x & 63;
  int row = blockIdx.x * 4 + w;
  const bf16* hr = hid + (size_t)row * 384;
  const float* W2[3] = {nw2, mw2, dw2};
  float outs[3];
#pragma unroll
  for (int t = 0; t < 3; t++) {
    float acc = (float)hr[t * 128 + lane] * W2[t][lane] +
                (float)hr[t * 128 + 64 + lane] * W2[t][64 + lane];
    for (int msk = 1; msk < 64; msk <<= 1) acc += __shfl_xor(acc, msk);
    outs[t] = acc;
  }
  if (lane == 0) {
    float xn = outs[0] + nb2[0];
    float n = (xn > 20.f) ? xn : log1pf(__expf(xn));
    float mu = 1.f / (1.f + __expf(-(outs[1] + mb2[0])));
    float delta = fmaxf(outs[2] + db2[0], 0.f);
    float surv = logf(n + 1e-8f) + logf(mu + 1e-8f) - delta;
    biasMain[row] = 0.1f * surv + maskBias[row];
  }
}

extern "C" void kernel_launch(void* const* d_in, const int* in_sizes, int n_in,
                              void* d_out, int out_size, void* d_ws, size_t ws_size,
                              hipStream_t stream) {
  const int B = 2, S = 2048, H = 768, I = 256;
  const int NH = 12, SNH = 4;
  const int M = B * S;  // 4096

  const float* x = (const float*)d_in[0];
  const int* mask = (const int*)d_in[1];
  const float* qw = (const float*)d_in[2];
  const float* qb = (const float*)d_in[3];
  const float* kw = (const float*)d_in[4];
  const float* kb = (const float*)d_in[5];
  const float* vw = (const float*)d_in[6];
  const float* vb = (const float*)d_in[7];
  const float* ow = (const float*)d_in[8];
  const float* ob = (const float*)d_in[9];
  const float* sp_w = (const float*)d_in[10];
  const float* sp_b = (const float*)d_in[11];
  const float* sa_in_w = (const float*)d_in[12];
  const float* sa_in_b = (const float*)d_in[13];
  const float* sa_out_w = (const float*)d_in[14];
  const float* sa_out_b = (const float*)d_in[15];
  const float* nw1 = (const float*)d_in[16];
  const float* nb1 = (const float*)d_in[17];
  const float* nw2 = (const float*)d_in[18];
  const float* nb2 = (const float*)d_in[19];
  const float* mw1 = (const float*)d_in[20];
  const float* mb1 = (const float*)d_in[21];
  const float* mw2 = (const float*)d_in[22];
  const float* mb2 = (const float*)d_in[23];
  const float* dw1 = (const float*)d_in[24];
  const float* db1 = (const float*)d_in[25];
  const float* dw2 = (const float*)d_in[26];
  const float* db2 = (const float*)d_in[27];

  char* ws = (char*)d_ws;
  size_t off = 0;
  auto alloc = [&](size_t bytes) -> void* {
    void* p = ws + off;
    off += (bytes + 255) & ~(size_t)255;
    return p;
  };

  // persistent
  bf16* xb = (bf16*)alloc((size_t)M * H * 2);
  bf16* wqb = (bf16*)alloc((size_t)H * H * 2);
  bf16* wkb = (bf16*)alloc((size_t)H * H * 2);
  bf16* wvb = (bf16*)alloc((size_t)H * H * 2);
  bf16* wob = (bf16*)alloc((size_t)H * H * 2);
  bf16* spwb = (bf16*)alloc((size_t)I * H * 2);
  bf16* sainb = (bf16*)alloc((size_t)(3 * I) * I * 2);
  bf16* saoutb = (bf16*)alloc((size_t)I * I * 2);
  bf16* w1pack = (bf16*)alloc((size_t)384 * 256 * 2);
  float* b1pack = (float*)alloc((size_t)384 * 4);
  float* maskBias = (float*)alloc((size_t)M * 4);
  float* biasMain = (float*)alloc((size_t)M * 4);

  size_t offMark = off;
  // phase A (scorer) scratch
  bf16* h0 = (bf16*)alloc((size_t)M * I * 2);
  bf16* qkv_s = (bf16*)alloc((size_t)M * (3 * I) * 2);
  bf16* vt_s = (bf16*)alloc((size_t)B * SNH * 64 * S * 2);
  bf16* attn_s = (bf16*)alloc((size_t)M * I * 2);
  bf16* h1 = (bf16*)alloc((size_t)M * I * 2);
  bf16* hid = (bf16*)alloc((size_t)M * 384 * 2);
  // phase B (main) scratch — overlays phase A (stream-serialized, phase A dead by then)
  off = offMark;
  bf16* Qm = (bf16*)alloc((size_t)M * H * 2);
  bf16* Km = (bf16*)alloc((size_t)M * H * 2);
  bf16* Vm = (bf16*)alloc((size_t)M * H * 2);
  bf16* vt_m = (bf16*)alloc((size_t)B * NH * 64 * S * 2);
  bf16* attn_m = (bf16*)alloc((size_t)M * H * 2);
  (void)ws_size; (void)in_sizes; (void)n_in; (void)out_size;

  auto cdiv = [](int a, int b) { return (a + b - 1) / b; };

  // converts
  cvt_bf16<<<cdiv(M * H / 4, 256), 256, 0, stream>>>(x, xb, M * H / 4);
  cvt_bf16<<<cdiv(H * H / 4, 256), 256, 0, stream>>>(qw, wqb, H * H / 4);
  cvt_bf16<<<cdiv(H * H / 4, 256), 256, 0, stream>>>(kw, wkb, H * H / 4);
  cvt_bf16<<<cdiv(H * H / 4, 256), 256, 0, stream>>>(vw, wvb, H * H / 4);
  cvt_bf16<<<cdiv(H * H / 4, 256), 256, 0, stream>>>(ow, wob, H * H / 4);
  cvt_bf16<<<cdiv(I * H / 4, 256), 256, 0, stream>>>(sp_w, spwb, I * H / 4);
  cvt_bf16<<<cdiv(3 * I * I / 4, 256), 256, 0, stream>>>(sa_in_w, sainb, 3 * I * I / 4);
  cvt_bf16<<<cdiv(I * I / 4, 256), 256, 0, stream>>>(sa_out_w, saoutb, I * I / 4);
  // pack the three 128x256 first-layer MLP weights into one [384,256] bf16
  cvt_bf16<<<cdiv(128 * 256 / 4, 256), 256, 0, stream>>>(nw1, w1pack, 128 * 256 / 4);
  cvt_bf16<<<cdiv(128 * 256 / 4, 256), 256, 0, stream>>>(mw1, w1pack + 128 * 256, 128 * 256 / 4);
  cvt_bf16<<<cdiv(128 * 256 / 4, 256), 256, 0, stream>>>(dw1, w1pack + 2 * 128 * 256, 128 * 256 / 4);
  hipMemcpyAsync(b1pack, nb1, 128 * sizeof(float), hipMemcpyDeviceToDevice, stream);
  hipMemcpyAsync(b1pack + 128, mb1, 128 * sizeof(float), hipMemcpyDeviceToDevice, stream);
  hipMemcpyAsync(b1pack + 256, db1, 128 * sizeof(float), hipMemcpyDeviceToDevice, stream);
  maskbias_k<<<cdiv(M, 256), 256, 0, stream>>>(mask, maskBias, M);

  // ---- scorer branch ----
  gemm_nt<0, 0><<<(M / 64) * (I / 64), 256, 0, stream>>>(xb, H, spwb, H, sp_b, h0, I, I / 64, H);
  gemm_nt<0, 0><<<(M / 64) * ((3 * I) / 64), 256, 0, stream>>>(h0, I, sainb, I, sa_in_b, qkv_s,
                                                               3 * I, (3 * I) / 64, I);
  vtrans<<<B * SNH * (S / 64), 256, 0, stream>>>(qkv_s, 3 * I, 2 * I, vt_s, SNH, S);
  flash_k<<<B * SNH * (S / 64), 256, 0, stream>>>(qkv_s, qkv_s + I, 3 * I, vt_s, maskBias,
                                                  attn_s, I, SNH, S, 0.125f);
  gemm_nt<0, 0><<<(M / 64) * (I / 64), 256, 0, stream>>>(attn_s, I, saoutb, I, sa_out_b, h1, I,
                                                         I / 64, I);
  // fused 3-MLP first layer: hid = relu(h1 @ w1pack^T + b1pack)  [M,384]
  gemm_nt<0, 1><<<(M / 64) * (384 / 64), 256, 0, stream>>>(h1, I, w1pack, I, b1pack, hid, 384,
                                                           384 / 64, I);
  surv_k<<<M / 4, 256, 0, stream>>>(hid, nw2, nb2, mw2, mb2, dw2, db2, maskBias, biasMain);

  // ---- main branch ----
  gemm_nt<0, 0><<<(M / 64) * (H / 64), 256, 0, stream>>>(xb, H, wqb, H, qb, Qm, H, H / 64, H);
  gemm_nt<0, 0><<<(M / 64) * (H / 64), 256, 0, stream>>>(xb, H, wkb, H, kb, Km, H, H / 64, H);
  gemm_nt<0, 0><<<(M / 64) * (H / 64), 256, 0, stream>>>(xb, H, wvb, H, vb, Vm, H, H / 64, H);
  vtrans<<<B * NH * (S / 64), 256, 0, stream>>>(Vm, H, 0, vt_m, NH, S);
  flash_k<<<B * NH * (S / 64), 256, 0, stream>>>(Qm, Km, H, vt_m, biasMain, attn_m, H, NH, S,
                                                 0.125f);
  gemm_nt<1, 0><<<(M / 64) * (H / 64), 256, 0, stream>>>(attn_m, H, wob, H, ob, d_out, H, H / 64,
                                                         H);
}